// Round 5
// baseline (10682.357 us; speedup 1.0000x reference)
//
#include <hip/hip_runtime.h>

// LSTM B=4096 T=336 I=21 H=50 OUT=24, fp32 in/out.
// Round 13: R12 retry with the VGPR/occupancy contract fixed.
//   R12 failed from REGISTER SPILL, not from the scheduling hypothesis:
//   __launch_bounds__(1024) let the compiler target 8 waves/EU -> VGPR
//   cap 64 < ~100 live (xp[8]=32 + weight frags 24 + staging ~15 + addr
//   ~15) -> xp/weights spilled to scratch -> 37 GB HBM writes, 11.4 ms.
//   Fix: __launch_bounds__(1024, 4) -> min 4 waves/EU -> VGPR cap 128.
//   1 wg/CU, 16 waves resident, exactly the skew design's assumption.
//   Hypothesis under test (unchanged from R12): 4 waves/SIMD at 4 rotated
//   phases hide the ~420 cyc/step neither-pipe latency bucket that 2
//   waves (R11, 204 us) could not. ph = (wv ^ (wv>>2)) & 3.
//     ph1: [XP, REC, PW]  ph2: [REC, XP, PW]  ph0/3: [REC, PW, XP]
//   Pre-committed: if dur >= 195 us with clean counters, 4-way TLP+skew
//   is refuted and the remaining bucket is barrier/dependency floor.
//   Numerics FROZEN from R11 (absmax ~0.004 expected).
//   Carried: xproj off the h-path (xp[s] f32 regs, 2-limb MFMA, bias as
//   C-init); REC = pure W_hh GEMM K=64 merged 4-deep 2-limb chain; x
//   staged per CH=8 chunk, double-buffered LDS; weights 2 fp16 limbs
//   pre-scaled for exp2 activations; h single fp16 in LDS; scaled cell
//   state c~ = 2log2e*c; pads compute h=0 exactly.
// LDS (halves), conflict-free B-frag reads (const + lane*16B):
//   hbuf[buf2][kb8][col16][8]   : h, k=0..63 (units 0..49 valid, rest 0)
//   xC[buf2][s8][kb4][col16][8] : x, k=0..31 (i<21 valid, rest 0)

#define T_SEQ 336
#define I_IN  21
#define HID   50
#define O_OUT 24
#define MB    16
#define NT    1024
#define MINW  4                      // min waves/EU -> VGPR cap 128
#define NWV   16                     // waves; 1 tile per wave
#define CH    8
#define NCH   42                     // 336 / 8
#define XELEM (CH * MB * I_IN)       // 2688 floats per chunk
#define NLD   3                      // ceil(2688 / 1024)
#define XBUFH (CH * 4 * 16 * 8)      // 4096 halves per x chunk buffer

#define HIDX(buf, kb, n, j) ((((buf)*8 + (kb))*16 + (n))*8 + (j))
#define XIDX(s, kb, n, j)   ((((s)*4 + (kb))*16 + (n))*8 + (j))

#define K_LOG2E 1.44269504088896340736f
#define C2SCALE (2.f * K_LOG2E)

typedef _Float16 f16x8 __attribute__((ext_vector_type(8)));
typedef float    f32x4 __attribute__((ext_vector_type(4)));

#define MFMA16(A, B, C) __builtin_amdgcn_mfma_f32_16x16x32_f16((A), (B), (C), 0, 0, 0)

static __device__ __forceinline__ float frcp(float v) { return __builtin_amdgcn_rcpf(v); }
static __device__ __forceinline__ float ex2(float v)  { return __builtin_amdgcn_exp2f(v); }
// gates pre-scaled: i,f,o by -log2e ; g by +2*log2e ; c~ is pre-scaled
static __device__ __forceinline__ float sigm2(float g) { return frcp(1.f + ex2(g)); }
static __device__ __forceinline__ float tanh2(float g) {      // tanh(true arg)
    return __builtin_fmaf(-2.f, frcp(1.f + ex2(g)), 1.f);
}
static __device__ __forceinline__ float tanh2s(float g) {     // 2log2e*tanh(true arg)
    return __builtin_fmaf(-2.f * C2SCALE, frcp(1.f + ex2(g)), C2SCALE);
}

// xproj build for chunk c+1, slot sp (compile-time in unrolled loop)
#define XPROJ(sp)                                                        \
    do {                                                                 \
        const f16x8 XN = *(const f16x8*)&xC[wb + (sp) * 512 + bfo];      \
        xp[(sp)] = MFMA16(Xh, XN, biasv);                                \
        xp[(sp)] = MFMA16(Xl, XN, xp[(sp)]);                             \
    } while (0)

// per-step xproj schedule block (slot s-1 at s=1..7, +slot 7 at s=7)
#define XPBLOCK()                                                        \
    do {                                                                 \
        if (dostg && s >= 1) XPROJ(s - 1);                               \
        if (dostg && s == CH - 1) XPROJ(CH - 1);                         \
    } while (0)

__global__ __launch_bounds__(NT, MINW)
void lstm_mfma13(const float* __restrict__ x,
                 const float* __restrict__ W_ih,
                 const float* __restrict__ W_hh,
                 const float* __restrict__ b_ih,
                 const float* __restrict__ b_hh,
                 const float* __restrict__ W_fc,
                 const float* __restrict__ b_fc,
                 float* __restrict__ out)
{
    __shared__ _Float16 hbuf[2 * 8 * 16 * 8];   // 2048 halves = 4 KB
    __shared__ _Float16 xC[2 * XBUFH];          // 8192 halves = 16 KB

    const int tid  = threadIdx.x;
    const int lane = tid & 63;
    const int wv   = tid >> 6;        // 0..15 == tile
    const int nl   = lane & 15;       // A: row-in-tile / B: batch col
    const int q    = lane >> 4;       // quad
    const int b0   = blockIdx.x * MB;
    const int ph   = (wv ^ (wv >> 2)) & 3;   // 4 distinct phases per SIMD

    // ---- zero-init LDS (pads must stay 0 forever; h(0)=0) ----
    for (int i = tid; i < 2 * 8 * 16 * 8; i += NT) hbuf[i] = (_Float16)0.f;
    for (int i = tid; i < 2 * XBUFH;      i += NT) xC[i]   = (_Float16)0.f;

    // ---- x staging precompute + issue chunk-0 loads ----
    // element e = tid + k*NT of a chunk: e = ((sI*16)+b)*21 + i
    const float* px[NLD];
    int  xdst[NLD];
    bool xv[NLD];
    float sv[NLD];
    #pragma unroll
    for (int k = 0; k < NLD; ++k) {
        const int e  = tid + k * NT;
        const int i  = e % I_IN;
        const int r  = e / I_IN;
        const int b  = r & 15;
        const int sIr = r >> 4;
        const int sI = (sIr < CH) ? sIr : 0;   // clamp tail (write is guarded)
        xv[k]   = (e < XELEM);
        px[k]   = x + ((size_t)(b0 + b) * T_SEQ + sI) * I_IN + i;
        xdst[k] = XIDX(sI, i >> 3, b, i & 7);
        sv[k]   = px[k][0];            // chunk 0 (overlaps weight build)
    }

    // ---- weights: 2-limb fp16 fragments + bias, built once, pre-scaled ----
    // A[m=nl][k]; packed row p = wv*16+nl -> unit=p>>2, gate=p&3
    f16x8 Wh[2], Wl[2];   // W_hh, K-chunks 0,1 (k=0..63)
    f16x8 Xh,    Xl;      // W_ih, single K-chunk (k=0..31)
    f32x4 biasv;
    {
        const int p    = wv * 16 + nl;
        const int unit = p >> 2, gate = p & 3;
        const bool vr  = (unit < HID);
        const float ws = (gate == 2) ? C2SCALE : (-K_LOG2E);
        const int orig = gate * HID + unit;       // i,f,g,o stacked row
        const int ub   = wv * 4 + q;              // unit for D rows q*4+r
        #pragma unroll
        for (int r = 0; r < 4; ++r) {
            const float bs = (r == 2) ? C2SCALE : (-K_LOG2E);
            biasv[r] = (ub < HID) ? (b_ih[r * HID + ub] + b_hh[r * HID + ub]) * bs : 0.f;
        }
        #pragma unroll
        for (int kc = 0; kc < 2; ++kc) {
            #pragma unroll
            for (int j = 0; j < 8; ++j) {
                const int k = kc * 32 + q * 8 + j;
                const float w = (vr && k < HID) ? W_hh[orig * HID + k] * ws : 0.f;
                const _Float16 hi = (_Float16)w;
                Wh[kc][j] = hi;
                Wl[kc][j] = (_Float16)(w - (float)hi);
            }
        }
        #pragma unroll
        for (int j = 0; j < 8; ++j) {
            const int k = q * 8 + j;
            const float w = (vr && k < I_IN) ? W_ih[orig * I_IN + k] * ws : 0.f;
            const _Float16 hi = (_Float16)w;
            Xh[j] = hi;
            Xl[j] = (_Float16)(w - (float)hi);
        }
    }

    __syncthreads();   // zero-init visible (chunk-0 loads drained by sv use)

    // ---- commit chunk 0 into xC buf 0; advance pointers to chunk 1 ----
    #pragma unroll
    for (int k = 0; k < NLD; ++k) {
        if (xv[k]) xC[xdst[k]] = (_Float16)sv[k];
        px[k] += CH * I_IN;
    }
    __syncthreads();   // chunk-0 x visible

    // pointwise: lane owns unit u0 = wv*4+q for batch nl (c~ in register)
    const int u0 = wv * 4 + q;
    const int hwo0 = ((u0 >> 3) * 16 + nl) * 8 + (u0 & 7);   // + buf*1024
    float cst0 = 0.f;    // scaled cell state c~ = 2log2e * c

    const _Float16* hb0 = &hbuf[HIDX(0, q, nl, 0)];
    const int bfo = ((q * 16) + nl) * 8;           // B-frag offset within step

    // ---- xp prologue: xproj+bias for chunk 0, in registers ----
    f32x4 xp[CH];
    {
        const int wb = 0;
        #pragma unroll
        for (int s = 0; s < CH; ++s) XPROJ(s);
    }

    for (int c = 0; c < NCH; ++c) {
        const int  rb    = (c & 1) * XBUFH;
        const int  wb    = ((c + 1) & 1) * XBUFH;
        const bool dostg = (c + 1) < NCH;
        #pragma unroll
        for (int s = 0; s < CH; ++s) {
            __syncthreads();   // hbuf[cur] (h) complete; xC[rb]/[wb] staged

            // staging loads for next chunk: first thing after the barrier
            if (s == 0 && dostg) {
                #pragma unroll
                for (int k = 0; k < NLD; ++k) sv[k] = px[k][0];
            }

            const int cur = s & 1, nxt = cur ^ 1;

            // ---- h B-frags: 2 contiguous b128 reads (critical path) ----
            const _Float16* hb = hb0 + cur * 1024;
            const f16x8 B0 = *(const f16x8*)(hb);
            const f16x8 B1 = *(const f16x8*)(hb + 512);

            // ---- phase 1: xproj BEFORE recurrent (phase shifter) ----
            if (ph == 1) XPBLOCK();

            // ---- recurrent MFMA: merged 4-deep 2-limb chain, init = xp ----
            __builtin_amdgcn_s_setprio(1);
            f32x4 a0 = xp[s];
            a0 = MFMA16(Wh[0], B0, a0);
            a0 = MFMA16(Wh[1], B1, a0);
            a0 = MFMA16(Wl[0], B0, a0);
            a0 = MFMA16(Wl[1], B1, a0);
            __builtin_amdgcn_s_setprio(0);

            // ---- phase 2: xproj between REC and PW ----
            if (ph == 2) XPBLOCK();

            // ---- pointwise cell update, in registers, unguarded ----
            // (pad units: weights+bias 0 -> h computes to exactly 0)
            {
                const float tg2 = tanh2s(a0[2]);
                const float cc  = __builtin_fmaf(sigm2(a0[1]), cst0,
                                                 sigm2(a0[0]) * tg2);
                cst0 = cc;
                const float h = sigm2(a0[3]) * tanh2(cc);
                hbuf[nxt * 1024 + hwo0] = (_Float16)h;
            }

            // ---- phases 0/3: xproj AFTER pointwise ----
            if (ph == 0 || ph == 3) XPBLOCK();

            // ---- commit staged x(next chunk) into the other x buffer ----
            if (s == 0 && dostg) {
                #pragma unroll
                for (int k = 0; k < NLD; ++k) {
                    if (xv[k]) xC[wb + xdst[k]] = (_Float16)sv[k];
                    px[k] += CH * I_IN;
                }
            }
        }
    }

    __syncthreads();
    // final h: t=335 -> s=7, wrote buf 0
    // ---- FC epilogue: 16*24 = 384 tasks (one-time) ----
    if (tid < MB * O_OUT) {
        const int b = tid / O_OUT, o = tid % O_OUT;
        float a = b_fc[o];
        for (int u = 0; u < HID; ++u) {
            const float hv = (float)hbuf[HIDX(0, u >> 3, b, u & 7)];
            a = __builtin_fmaf(hv, W_fc[o * HID + u], a);
        }
        out[(size_t)(b0 + b) * O_OUT + o] = a;
    }
}

extern "C" void kernel_launch(void* const* d_in, const int* in_sizes, int n_in,
                              void* d_out, int out_size, void* d_ws, size_t ws_size,
                              hipStream_t stream)
{
    const float* x    = (const float*)d_in[0];
    const float* W_ih = (const float*)d_in[1];
    const float* W_hh = (const float*)d_in[2];
    const float* b_ih = (const float*)d_in[3];
    const float* b_hh = (const float*)d_in[4];
    const float* W_fc = (const float*)d_in[5];
    const float* b_fc = (const float*)d_in[6];
    float* out = (float*)d_out;

    lstm_mfma13<<<dim3(4096 / MB), dim3(NT), 0, stream>>>(
        x, W_ih, W_hh, b_ih, b_hh, W_fc, b_fc, out);
}

// Round 8
// 338.099 us; speedup vs baseline: 31.5953x; 31.5953x over previous
//
#include <hip/hip_runtime.h>

// LSTM B=4096 T=336 I=21 H=50 OUT=24, fp32 in/out.
// Round 16: R15 + xp-clobber bugfix -> first VALID run of the 4-wave-skew
// experiment.
//   BUG (introduced R11, latent since): for the XP-before-REC phase group
//   (ph==1), XPROJ(CH-1) at s==CH-1 overwrote xp[CH-1] with the NEXT
//   chunk's projection BEFORE a0 = xp[s] read it -> last step of every
//   non-final chunk used the wrong x for 1/4 of units. Error decayed
//   through forget gates: CH=8 -> absmax ~3e-3 (R11-R13, passed, wrongly
//   attributed to the c~ reparam), CH=6 -> 8.3e-3 (R15, failed).
//   FIX: hoist the xp[s] read (a0init) above the phase-1 XP block.
//   Everything else identical to R15:
//   - NT=1024, 16 waves, 1 tile/wave; __attribute__((amdgpu_waves_per_eu(4)))
//     -> VGPR cap 128 (min-only form; the (4,4) pin was R14's suspect).
//   - CH=6 (xp 24 VGPRs, NLD=2) -> ~93 live regs under the 128 cap.
//   - ph = (wv^(wv>>2))&3: ph1 [XP,REC,PW], ph2 [REC,XP,PW], ph0/3
//     [REC,PW,XP]; s_setprio(1) around REC.
//   Hypothesis: 4 skewed waves/SIMD hide the ~420 cyc/step neither-pipe
//   bucket that 2 waves (R11, 204 us) could not.
//   Pre-committed: VGPR=64/spill -> abandon NT=1024, revert to R11+fix;
//   clean + dur>=195us -> refuted, R11+fix is the floor candidate.
//   Carried: xproj off the h-path (xp[s] f32 regs, 2-limb MFMA, bias as
//   C-init); REC = pure W_hh GEMM K=64 merged 4-deep 2-limb chain; x
//   staged per CH=6 chunk, double-buffered LDS; weights 2 fp16 limbs
//   pre-scaled for exp2 activations; h single fp16 in LDS; scaled cell
//   state c~ = 2log2e*c; pads compute h=0 exactly.
// LDS (halves), conflict-free B-frag reads (const + lane*16B):
//   hbuf[buf2][kb8][col16][8]   : h, k=0..63 (units 0..49 valid, rest 0)
//   xC[buf2][s6][kb4][col16][8] : x, k=0..31 (i<21 valid, rest 0)

#define T_SEQ 336
#define I_IN  21
#define HID   50
#define O_OUT 24
#define MB    16
#define NT    1024
#define NWV   16                     // waves; 1 tile per wave
#define CH    6
#define NCH   56                     // 336 / 6
#define XELEM (CH * MB * I_IN)       // 2016 floats per chunk
#define NLD   2                      // ceil(2016 / 1024)
#define XBUFH (CH * 4 * 16 * 8)      // 3072 halves per x chunk buffer

#define HIDX(buf, kb, n, j) ((((buf)*8 + (kb))*16 + (n))*8 + (j))
#define XIDX(s, kb, n, j)   ((((s)*4 + (kb))*16 + (n))*8 + (j))

#define K_LOG2E 1.44269504088896340736f
#define C2SCALE (2.f * K_LOG2E)

typedef _Float16 f16x8 __attribute__((ext_vector_type(8)));
typedef float    f32x4 __attribute__((ext_vector_type(4)));

#define MFMA16(A, B, C) __builtin_amdgcn_mfma_f32_16x16x32_f16((A), (B), (C), 0, 0, 0)

static __device__ __forceinline__ float frcp(float v) { return __builtin_amdgcn_rcpf(v); }
static __device__ __forceinline__ float ex2(float v)  { return __builtin_amdgcn_exp2f(v); }
// gates pre-scaled: i,f,o by -log2e ; g by +2*log2e ; c~ is pre-scaled
static __device__ __forceinline__ float sigm2(float g) { return frcp(1.f + ex2(g)); }
static __device__ __forceinline__ float tanh2(float g) {      // tanh(true arg)
    return __builtin_fmaf(-2.f, frcp(1.f + ex2(g)), 1.f);
}
static __device__ __forceinline__ float tanh2s(float g) {     // 2log2e*tanh(true arg)
    return __builtin_fmaf(-2.f * C2SCALE, frcp(1.f + ex2(g)), C2SCALE);
}

// xproj build for chunk c+1, slot sp (compile-time in unrolled loop)
#define XPROJ(sp)                                                        \
    do {                                                                 \
        const f16x8 XN = *(const f16x8*)&xC[wb + (sp) * 512 + bfo];      \
        xp[(sp)] = MFMA16(Xh, XN, biasv);                                \
        xp[(sp)] = MFMA16(Xl, XN, xp[(sp)]);                             \
    } while (0)

// per-step xproj schedule block (slot s-1 at s=1..CH-1, +slot CH-1 at s=CH-1)
// NOTE: safe to run anywhere in the step body ONLY because a0init snapshots
// xp[s] first (the s==CH-1 XPROJ clobbers xp[CH-1] for the next chunk).
#define XPBLOCK()                                                        \
    do {                                                                 \
        if (dostg && s >= 1) XPROJ(s - 1);                               \
        if (dostg && s == CH - 1) XPROJ(CH - 1);                         \
    } while (0)

__global__ __launch_bounds__(NT) __attribute__((amdgpu_waves_per_eu(4)))
void lstm_mfma16(const float* __restrict__ x,
                 const float* __restrict__ W_ih,
                 const float* __restrict__ W_hh,
                 const float* __restrict__ b_ih,
                 const float* __restrict__ b_hh,
                 const float* __restrict__ W_fc,
                 const float* __restrict__ b_fc,
                 float* __restrict__ out)
{
    __shared__ _Float16 hbuf[2 * 8 * 16 * 8];   // 2048 halves = 4 KB
    __shared__ _Float16 xC[2 * XBUFH];          // 6144 halves = 12 KB

    const int tid  = threadIdx.x;
    const int lane = tid & 63;
    const int wv   = tid >> 6;        // 0..15 == tile
    const int nl   = lane & 15;       // A: row-in-tile / B: batch col
    const int q    = lane >> 4;       // quad
    const int b0   = blockIdx.x * MB;
    const int ph   = (wv ^ (wv >> 2)) & 3;   // 4 distinct phases per SIMD

    // ---- zero-init LDS (pads must stay 0 forever; h(0)=0) ----
    for (int i = tid; i < 2 * 8 * 16 * 8; i += NT) hbuf[i] = (_Float16)0.f;
    for (int i = tid; i < 2 * XBUFH;      i += NT) xC[i]   = (_Float16)0.f;

    // ---- x staging precompute + issue chunk-0 loads ----
    // element e = tid + k*NT of a chunk: e = ((sI*16)+b)*21 + i
    const float* px[NLD];
    int  xdst[NLD];
    bool xv[NLD];
    float sv[NLD];
    #pragma unroll
    for (int k = 0; k < NLD; ++k) {
        const int e  = tid + k * NT;
        const int i  = e % I_IN;
        const int r  = e / I_IN;
        const int b  = r & 15;
        const int sIr = r >> 4;
        const int sI = (sIr < CH) ? sIr : 0;   // clamp tail (write is guarded)
        xv[k]   = (e < XELEM);
        px[k]   = x + ((size_t)(b0 + b) * T_SEQ + sI) * I_IN + i;
        xdst[k] = XIDX(sI, i >> 3, b, i & 7);
        sv[k]   = px[k][0];            // chunk 0 (overlaps weight build)
    }

    // ---- weights: 2-limb fp16 fragments + bias, built once, pre-scaled ----
    // A[m=nl][k]; packed row p = wv*16+nl -> unit=p>>2, gate=p&3
    f16x8 Wh[2], Wl[2];   // W_hh, K-chunks 0,1 (k=0..63)
    f16x8 Xh,    Xl;      // W_ih, single K-chunk (k=0..31)
    f32x4 biasv;
    {
        const int p    = wv * 16 + nl;
        const int unit = p >> 2, gate = p & 3;
        const bool vr  = (unit < HID);
        const float ws = (gate == 2) ? C2SCALE : (-K_LOG2E);
        const int orig = gate * HID + unit;       // i,f,g,o stacked row
        const int ub   = wv * 4 + q;              // unit for D rows q*4+r
        #pragma unroll
        for (int r = 0; r < 4; ++r) {
            const float bs = (r == 2) ? C2SCALE : (-K_LOG2E);
            biasv[r] = (ub < HID) ? (b_ih[r * HID + ub] + b_hh[r * HID + ub]) * bs : 0.f;
        }
        #pragma unroll
        for (int kc = 0; kc < 2; ++kc) {
            #pragma unroll
            for (int j = 0; j < 8; ++j) {
                const int k = kc * 32 + q * 8 + j;
                const float w = (vr && k < HID) ? W_hh[orig * HID + k] * ws : 0.f;
                const _Float16 hi = (_Float16)w;
                Wh[kc][j] = hi;
                Wl[kc][j] = (_Float16)(w - (float)hi);
            }
        }
        #pragma unroll
        for (int j = 0; j < 8; ++j) {
            const int k = q * 8 + j;
            const float w = (vr && k < I_IN) ? W_ih[orig * I_IN + k] * ws : 0.f;
            const _Float16 hi = (_Float16)w;
            Xh[j] = hi;
            Xl[j] = (_Float16)(w - (float)hi);
        }
    }

    __syncthreads();   // zero-init visible (chunk-0 loads drained by sv use)

    // ---- commit chunk 0 into xC buf 0; advance pointers to chunk 1 ----
    #pragma unroll
    for (int k = 0; k < NLD; ++k) {
        if (xv[k]) xC[xdst[k]] = (_Float16)sv[k];
        px[k] += CH * I_IN;
    }
    __syncthreads();   // chunk-0 x visible

    // pointwise: lane owns unit u0 = wv*4+q for batch nl (c~ in register)
    const int u0 = wv * 4 + q;
    const int hwo0 = ((u0 >> 3) * 16 + nl) * 8 + (u0 & 7);   // + buf*1024
    float cst0 = 0.f;    // scaled cell state c~ = 2log2e * c

    const _Float16* hb0 = &hbuf[HIDX(0, q, nl, 0)];
    const int bfo = ((q * 16) + nl) * 8;           // B-frag offset within step

    // ---- xp prologue: xproj+bias for chunk 0, in registers ----
    f32x4 xp[CH];
    {
        const int wb = 0;
        #pragma unroll
        for (int s = 0; s < CH; ++s) XPROJ(s);
    }

    for (int c = 0; c < NCH; ++c) {
        const int  rb    = (c & 1) * XBUFH;
        const int  wb    = ((c + 1) & 1) * XBUFH;
        const bool dostg = (c + 1) < NCH;
        #pragma unroll
        for (int s = 0; s < CH; ++s) {
            __syncthreads();   // hbuf[cur] (h) complete; xC[rb]/[wb] staged

            // staging loads for next chunk: first thing after the barrier
            if (s == 0 && dostg) {
                #pragma unroll
                for (int k = 0; k < NLD; ++k) sv[k] = px[k][0];
            }

            const int cur = s & 1, nxt = cur ^ 1;

            // ---- h B-frags: 2 contiguous b128 reads (critical path) ----
            const _Float16* hb = hb0 + cur * 1024;
            const f16x8 B0 = *(const f16x8*)(hb);
            const f16x8 B1 = *(const f16x8*)(hb + 512);

            // ---- BUGFIX: snapshot xp[s] BEFORE any XPROJ can clobber it
            //      (ph==1 at s==CH-1 overwrites xp[CH-1] for next chunk) ----
            const f32x4 a0init = xp[s];

            // ---- phase 1: xproj BEFORE recurrent (phase shifter) ----
            if (ph == 1) XPBLOCK();

            // ---- recurrent MFMA: merged 4-deep 2-limb chain, init = xp ----
            __builtin_amdgcn_s_setprio(1);
            f32x4 a0 = a0init;
            a0 = MFMA16(Wh[0], B0, a0);
            a0 = MFMA16(Wh[1], B1, a0);
            a0 = MFMA16(Wl[0], B0, a0);
            a0 = MFMA16(Wl[1], B1, a0);
            __builtin_amdgcn_s_setprio(0);

            // ---- phase 2: xproj between REC and PW ----
            if (ph == 2) XPBLOCK();

            // ---- pointwise cell update, in registers, unguarded ----
            // (pad units: weights+bias 0 -> h computes to exactly 0)
            {
                const float tg2 = tanh2s(a0[2]);
                const float cc  = __builtin_fmaf(sigm2(a0[1]), cst0,
                                                 sigm2(a0[0]) * tg2);
                cst0 = cc;
                const float h = sigm2(a0[3]) * tanh2(cc);
                hbuf[nxt * 1024 + hwo0] = (_Float16)h;
            }

            // ---- phases 0/3: xproj AFTER pointwise ----
            if (ph == 0 || ph == 3) XPBLOCK();

            // ---- commit staged x(next chunk) into the other x buffer ----
            if (s == 0 && dostg) {
                #pragma unroll
                for (int k = 0; k < NLD; ++k) {
                    if (xv[k]) xC[wb + xdst[k]] = (_Float16)sv[k];
                    px[k] += CH * I_IN;
                }
            }
        }
    }

    __syncthreads();
    // final h: t=335 -> s=5, wrote buf 0
    // ---- FC epilogue: 16*24 = 384 tasks (one-time) ----
    if (tid < MB * O_OUT) {
        const int b = tid / O_OUT, o = tid % O_OUT;
        float a = b_fc[o];
        for (int u = 0; u < HID; ++u) {
            const float hv = (float)hbuf[HIDX(0, u >> 3, b, u & 7)];
            a = __builtin_fmaf(hv, W_fc[o * HID + u], a);
        }
        out[(size_t)(b0 + b) * O_OUT + o] = a;
    }
}

extern "C" void kernel_launch(void* const* d_in, const int* in_sizes, int n_in,
                              void* d_out, int out_size, void* d_ws, size_t ws_size,
                              hipStream_t stream)
{
    const float* x    = (const float*)d_in[0];
    const float* W_ih = (const float*)d_in[1];
    const float* W_hh = (const float*)d_in[2];
    const float* b_ih = (const float*)d_in[3];
    const float* b_hh = (const float*)d_in[4];
    const float* W_fc = (const float*)d_in[5];
    const float* b_fc = (const float*)d_in[6];
    float* out = (float*)d_out;

    lstm_mfma16<<<dim3(4096 / MB), dim3(NT), 0, stream>>>(
        x, W_ih, W_hh, b_ih, b_hh, W_fc, b_fc, out);
}